// Round 1
// baseline (229.173 us; speedup 1.0000x reference)
//
#include <hip/hip_runtime.h>

// ReactDiffDynamics: dUdt = a*lap(U)/dx^2-form + U - U^3 - k - V ; dVdt = b*lap(V) + U - V
// Periodic 5-point Laplacian (jnp.roll semantics), B=64, H=W=512, fp32.
// Memory-bound: ~268 MB total traffic, roofline ~43 us @ 6.3 TB/s.

constexpr int B = 64;
constexpr int H = 512;
constexpr int W = 512;
constexpr int W4 = W / 4;          // float4 groups per row
constexpr int PLANE = H * W;       // elements per channel plane

__global__ __launch_bounds__(256) void react_diff_kernel(
    const float* __restrict__ x,       // (B, 2, H, W)
    const float* __restrict__ params,  // (B, 3)
    float* __restrict__ out)           // (B, 2, H, W)
{
    const float inv_dx2 = 240.25f;  // 1/dx^2, dx = 2/31

    int tid = blockIdx.x * blockDim.x + threadIdx.x;   // [0, B*H*W4)
    int wv  = tid % W4;
    int rem = tid / W4;
    int h   = rem % H;
    int b   = rem / H;

    int hn = (h == 0)     ? H - 1 : h - 1;   // roll(+1): f[h-1]
    int hs = (h == H - 1) ? 0     : h + 1;   // roll(-1): f[h+1]
    int w0 = wv * 4;
    int wW = (wv == 0)      ? W - 1 : w0 - 1;  // west wrap
    int wE = (wv == W4 - 1) ? 0     : w0 + 4;  // east wrap

    const float* Ub = x + (size_t)b * 2 * PLANE;
    const float* Vb = Ub + PLANE;

    const size_t rc = (size_t)h  * W;
    const size_t rn = (size_t)hn * W;
    const size_t rs = (size_t)hs * W;

    float4 Uc = ((const float4*)(Ub + rc))[wv];
    float4 Un = ((const float4*)(Ub + rn))[wv];
    float4 Us = ((const float4*)(Ub + rs))[wv];
    float  Uw = Ub[rc + wW];
    float  Ue = Ub[rc + wE];

    float4 Vc = ((const float4*)(Vb + rc))[wv];
    float4 Vn = ((const float4*)(Vb + rn))[wv];
    float4 Vs = ((const float4*)(Vb + rs))[wv];
    float  Vw = Vb[rc + wW];
    float  Ve = Vb[rc + wE];

    float pa = params[b * 3 + 0];
    float pb = params[b * 3 + 1];
    float pk = params[b * 3 + 2];

    float4 lapU, lapV;
    lapU.x = Un.x + Us.x + Uw   + Uc.y - 4.0f * Uc.x;
    lapU.y = Un.y + Us.y + Uc.x + Uc.z - 4.0f * Uc.y;
    lapU.z = Un.z + Us.z + Uc.y + Uc.w - 4.0f * Uc.z;
    lapU.w = Un.w + Us.w + Uc.z + Ue   - 4.0f * Uc.w;

    lapV.x = Vn.x + Vs.x + Vw   + Vc.y - 4.0f * Vc.x;
    lapV.y = Vn.y + Vs.y + Vc.x + Vc.z - 4.0f * Vc.y;
    lapV.z = Vn.z + Vs.z + Vc.y + Vc.w - 4.0f * Vc.z;
    lapV.w = Vn.w + Vs.w + Vc.z + Ve   - 4.0f * Vc.w;

    float4 dU, dV;
    dU.x = pa * lapU.x * inv_dx2 + Uc.x - Uc.x * Uc.x * Uc.x - pk - Vc.x;
    dU.y = pa * lapU.y * inv_dx2 + Uc.y - Uc.y * Uc.y * Uc.y - pk - Vc.y;
    dU.z = pa * lapU.z * inv_dx2 + Uc.z - Uc.z * Uc.z * Uc.z - pk - Vc.z;
    dU.w = pa * lapU.w * inv_dx2 + Uc.w - Uc.w * Uc.w * Uc.w - pk - Vc.w;

    dV.x = pb * lapV.x * inv_dx2 + Uc.x - Vc.x;
    dV.y = pb * lapV.y * inv_dx2 + Uc.y - Vc.y;
    dV.z = pb * lapV.z * inv_dx2 + Uc.z - Vc.z;
    dV.w = pb * lapV.w * inv_dx2 + Uc.w - Vc.w;

    float* ob = out + (size_t)b * 2 * PLANE;
    ((float4*)(ob + rc))[wv]         = dU;
    ((float4*)(ob + PLANE + rc))[wv] = dV;
}

extern "C" void kernel_launch(void* const* d_in, const int* in_sizes, int n_in,
                              void* d_out, int out_size, void* d_ws, size_t ws_size,
                              hipStream_t stream) {
    // d_in[0] = t (1 float, unused), d_in[1] = x (B,2,H,W), d_in[2] = params (B,3)
    const float* x      = (const float*)d_in[1];
    const float* params = (const float*)d_in[2];
    float* out          = (float*)d_out;

    int total_vec = B * H * W4;            // 4,194,304 threads
    int block = 256;
    int grid = total_vec / block;          // 16384 blocks
    react_diff_kernel<<<grid, block, 0, stream>>>(x, params, out);
}